// Round 18
// baseline (81.162 us; speedup 1.0000x reference)
//
#include <hip/hip_runtime.h>
#include <stdint.h>
#include <stddef.h>

typedef unsigned int u32;
typedef unsigned long long u64;
typedef unsigned short u16;
typedef unsigned char u8;

#define NB 4
#define NLEV 5
#define NCH 72      // A*C = 9*8
#define NREGCH 36   // A*4
#define TOPK 1000
#define NCAND 5000  // NLEV*TOPK
#define NDET 300
#define NBINS 16384       // fallback hist: sigmoid float bits >> 16
#define RNB 4096          // counting-rank buckets (fast path)
#define CAP 8192          // per-(b,level) filtered-candidate buffer
#define FASTCAP 2048      // fast-path key limit (2 keys/thread @ 1024 thr)
#define CHUNK 8192
#define NCHUNK_IMG 50     // 36+9+3+1+1
#define DCH 512           // NMS rank-prefix chunk
#define DW 8              // u64 words per suppression row
#define IMGSZ 512.0f
#define SCORE_TH 0.05f
#define NMS_TH 0.5f
#define BBOX_CLIP_F 4.135166556742356f

__constant__ int c_f[NLEV]    = {64, 32, 16, 8, 4};
__constant__ int c_Nloc[NLEV] = {4096, 1024, 256, 64, 16};
__constant__ int c_lg2[NLEV]  = {12, 10, 8, 6, 4};
// logit prefilter thresholds: ~1400 expected survivors at levels 0-3 (10-sigma
// margins vs both TOPK=1000 and FASTCAP=2048); level 4 unfiltered (1152 total).
__constant__ float c_tau[NLEV] = {2.594f, 2.075f, 1.433f, 0.513f, -1e30f};
// counting-rank bucket shifts: (0x3F800000 - bits(sigmoid(tau))) >> shift < RNB
__constant__ int c_rshift[NLEV] = {10, 10, 11, 12, 18};
// per-level chunk layout inside a group's CAP region (atomic-free k_filter)
__constant__ int c_nch[NLEV]  = {36, 9, 3, 1, 1};
__constant__ int c_clo[NLEV]  = {0, 36, 45, 48, 49};
__constant__ int c_ccap[NLEV] = {227, 910, 2730, 8192, 8192};  // CAP/nch

// ---- XLA-CPU-style sigmoid: logistic(x) = 0.5 + 0.5*tanh(0.5*x), fast-tanh poly, no FMA ----
__device__ __forceinline__ float xla_tanh_f32(float x) {
  float ax = fabsf(x);
  float xc = fminf(fmaxf(x, -7.90531110763549805f), 7.90531110763549805f);
  float x2 = __fmul_rn(xc, xc);
  float p = -2.76076847742355e-16f;
  p = __fadd_rn(__fmul_rn(x2, p), 2.00018790482477e-13f);
  p = __fadd_rn(__fmul_rn(x2, p), -8.60467152213735e-11f);
  p = __fadd_rn(__fmul_rn(x2, p), 5.12229709037114e-08f);
  p = __fadd_rn(__fmul_rn(x2, p), 1.48572235717979e-05f);
  p = __fadd_rn(__fmul_rn(x2, p), 6.37261928875436e-04f);
  p = __fadd_rn(__fmul_rn(x2, p), 4.89352455891786e-03f);
  float num = __fmul_rn(xc, p);
  float q = 1.19825839466702e-06f;
  q = __fadd_rn(__fmul_rn(x2, q), 1.18534705686654e-04f);
  q = __fadd_rn(__fmul_rn(x2, q), 2.26843463243900e-03f);
  q = __fadd_rn(__fmul_rn(x2, q), 4.89352518554385e-03f);
  float r = __fdiv_rn(num, q);
  return (ax < 0.0004f) ? x : r;
}
__device__ __forceinline__ float sigmoid_ref(float x) {
  return __fadd_rn(0.5f, __fmul_rn(0.5f, xla_tanh_f32(__fmul_rn(0.5f, x))));
}

struct ClsPtrs { const float* p[NLEV]; };
struct LevelPtrs { const float* reg[NLEV]; const float* anc[NLEV]; };

__device__ __forceinline__ void chunk_map(int bid, int& b, int& level, int& chunk) {
  b = bid / NCHUNK_IMG;
  int cid = bid % NCHUNK_IMG;
  if      (cid < 36) { level = 0; chunk = cid; }
  else if (cid < 45) { level = 1; chunk = cid - 36; }
  else if (cid < 48) { level = 2; chunk = cid - 45; }
  else if (cid < 49) { level = 3; chunk = cid - 48; }
  else               { level = 4; chunk = cid - 49; }
}

// exact BoxCoder decode + clip (identical _rn sequence as all passing rounds)
__device__ __forceinline__ float4 decode_box(const LevelPtrs& lp, int b, int lv, u32 e) {
  u32 anc = e >> 3;              // loc*9 + a
  int a = (int)(anc % 9u);
  int loc = (int)(anc / 9u);
  int f = c_f[lv];
  int Nloc = f * f;
  const float* rp = lp.reg[lv];
  const float* ap = lp.anc[lv] + (size_t)anc * 4;
  float r0 = rp[((size_t)b * NREGCH + (a * 4 + 0)) * Nloc + loc];
  float r1 = rp[((size_t)b * NREGCH + (a * 4 + 1)) * Nloc + loc];
  float r2 = rp[((size_t)b * NREGCH + (a * 4 + 2)) * Nloc + loc];
  float r3 = rp[((size_t)b * NREGCH + (a * 4 + 3)) * Nloc + loc];
  float a0 = ap[0], a1 = ap[1], a2 = ap[2], a3 = ap[3];
  float aw = __fsub_rn(a2, a0);
  float ah = __fsub_rn(a3, a1);
  float acx = __fadd_rn(a0, __fmul_rn(0.5f, aw));
  float acy = __fadd_rn(a1, __fmul_rn(0.5f, ah));
  float dw = fminf(r2, BBOX_CLIP_F);
  float dh = fminf(r3, BBOX_CLIP_F);
  float pcx = __fadd_rn(__fmul_rn(r0, aw), acx);
  float pcy = __fadd_rn(__fmul_rn(r1, ah), acy);
  float pw = __fmul_rn(expf(dw), aw);
  float ph = __fmul_rn(expf(dh), ah);
  float hx = __fmul_rn(0.5f, pw);
  float hy = __fmul_rn(0.5f, ph);
  float4 v;
  v.x = fminf(fmaxf(__fsub_rn(pcx, hx), 0.0f), IMGSZ);
  v.y = fminf(fmaxf(__fsub_rn(pcy, hy), 0.0f), IMGSZ);
  v.z = fminf(fmaxf(__fadd_rn(pcx, hx), 0.0f), IMGSZ);
  v.w = fminf(fmaxf(__fadd_rn(pcy, hy), 0.0f), IMGSZ);
  return v;
}

// ---- K1: logit-prefilter, ATOMIC-FREE: per-chunk region writes + per-block count ----
__global__ __launch_bounds__(256)
void k_filter(ClsPtrs cp, u32* __restrict__ bcnt, u64* __restrict__ sel) {
  int b, level, chunk;
  chunk_map(blockIdx.x, b, level, chunk);
  int Nloc = c_Nloc[level], lg2 = c_lg2[level];
  int Nsc = Nloc * NCH;
  int g = b * NLEV + level;
  const float* cls = cp.p[level] + (size_t)b * Nsc;
  float tau = c_tau[level];
  int base = chunk * CHUNK;
  int end = base + CHUNK; if (end > Nsc) end = Nsc;
  int wid = threadIdx.x >> 6, lane = threadIdx.x & 63;
  u64 lowm = (1ull << lane) - 1ull;
  __shared__ u32 wcnt[4];
  u32 mycnt = 0;
  for (int i = base + threadIdx.x; i < end; i += 256) {
    u64 mk = __ballot((int)(cls[i] > tau));
    mycnt += (u32)__popcll(mk);
  }
  if (lane == 0) wcnt[wid] = mycnt;
  __syncthreads();
  u32 wbase = 0, tot = 0;
  for (int w = 0; w < 4; ++w) { u32 c = wcnt[w]; if (w < wid) wbase += c; tot += c; }
  if (threadIdx.x == 0) bcnt[blockIdx.x] = tot;   // always written: no memset needed
  if (!tot) return;
  u32 ccap = (u32)c_ccap[level];
  size_t regbase = (size_t)g * CAP + (size_t)chunk * ccap;
  u32 run = 0;
  for (int i = base + threadIdx.x; i < end; i += 256) {
    float x = cls[i];
    bool selp = x > tau;                 // monotone sigmoid => logit-space superset filter
    u64 mk = __ballot((int)selp);
    if (selp) {
      u32 pos = wbase + run + (u32)__popcll(mk & lowm);
      if (pos < ccap) {
        u32 bits = __float_as_uint(sigmoid_ref(x));
        int ch = i >> lg2;
        int loc = i & (Nloc - 1);
        u32 e = (u32)(loc * NCH + ch);   // flat score index ((y*f+x)*9+a)*8+c
        sel[regbase + pos] = ((u64)bits << 32) | (u32)(~e);
      }
    }
    run += (u32)__popcll(mk);
  }
}

// ---- K2: exact top-1000 via LDS counting-rank + fused decode; guarded fast path ----
__global__ __launch_bounds__(1024)
void k_rank(ClsPtrs cp, LevelPtrs lp, const u32* __restrict__ bcnt,
            const u64* __restrict__ sel,
            float* __restrict__ cand_s, u32* __restrict__ cand_t,
            float4* __restrict__ cand_box) {
  __shared__ union {
    struct { u64 keysC[FASTCAP]; u64 keys2[FASTCAP]; u32 hist[RNB]; u32 pfx[RNB]; } f; // 64 KB
    u32 histfb[NBINS];                                              // 64 KB
    u64 keysfb[CAP];                                                // 64 KB
  } sh;
  __shared__ u32 part[1024];
  __shared__ u32 ccnt[36];
  __shared__ u32 cbase[37];
  __shared__ u32 s_ovf;
  __shared__ u32 s_last;
  __shared__ u32 s_cnt;
  __shared__ int s_cut;
  int g = blockIdx.x;
  int b = g / NLEV, l = g % NLEV;
  int Nloc = c_Nloc[l], lg2 = c_lg2[l];
  int Nsc = Nloc * NCH;
  int tid = threadIdx.x;
  int lane = tid & 63;
  u64 lowm = (1ull << lane) - 1ull;
  int obase = b * NCAND + l * TOPK;
  int nch = c_nch[l], clo = c_clo[l];
  u32 ccap = (u32)c_ccap[l];
  if (tid < nch) ccnt[tid] = bcnt[b * NCHUNK_IMG + clo + tid];
  __syncthreads();
  if (tid == 0) {
    u32 a = 0, ovf = 0;
    for (int c = 0; c < nch; ++c) { cbase[c] = a; a += ccnt[c]; if (ccnt[c] > ccap) ovf = 1; }
    cbase[nch] = a; s_ovf = ovf;
  }
  __syncthreads();
  u32 cnt = cbase[nch];
  bool fast = (cnt >= TOPK) && (cnt <= FASTCAP) && !s_ovf;
  if (fast) {
    u32 m = cnt;
    int shift = c_rshift[l];
    // PARALLEL compaction: each element binary-searches its chunk via cbase
    for (u32 i = tid; i < m; i += 1024) {
      int lo = 0, h2 = nch - 1;
      while (lo < h2) { int mid = (lo + h2 + 1) >> 1; if (cbase[mid] <= i) lo = mid; else h2 = mid - 1; }
      sh.f.keysC[i] = sel[(size_t)g * CAP + (size_t)lo * ccap + (i - cbase[lo])];
    }
    for (int i = tid; i < RNB; i += 1024) sh.f.hist[i] = 0;
    if (tid == 0) s_last = 0;
    __syncthreads();
    u64 k0a = ((u32)tid < m)        ? sh.f.keysC[tid]        : 0ULL;
    u64 k0b = ((u32)tid + 1024 < m) ? sh.f.keysC[tid + 1024] : 0ULL;
    // bucket: monotone DECREASING in key; clamp handles tails exactly
    auto bkt_of = [&](u64 k) -> int {
      int d = (int)0x3F800000 - (int)(u32)(k >> 32);
      if (d < 0) d = 0;
      int bq = d >> shift;
      return bq > RNB - 1 ? RNB - 1 : bq;
    };
    int ba = bkt_of(k0a), bb = bkt_of(k0b);
    if ((u32)tid < m)        atomicAdd(&sh.f.hist[ba], 1u);
    if ((u32)tid + 1024 < m) atomicAdd(&sh.f.hist[bb], 1u);
    __syncthreads();
    // exclusive prefix scan of hist[RNB] -> pfx
    {
      int t4 = tid * 4;
      u32 h0 = sh.f.hist[t4], h1 = sh.f.hist[t4 + 1], h2 = sh.f.hist[t4 + 2], h3 = sh.f.hist[t4 + 3];
      u32 s4 = h0 + h1 + h2 + h3;
      u32 x = s4;
      for (int d = 1; d < 64; d <<= 1) { u32 y = __shfl_up(x, d); if (lane >= d) x += y; }
      if (lane == 63) part[tid >> 6] = x;
      __syncthreads();
      if (tid == 0) { u32 a = 0; for (int w = 0; w < 16; ++w) { u32 c = part[w]; part[w] = a; a += c; } }
      __syncthreads();
      u32 base2 = part[tid >> 6] + (x - s4);
      sh.f.pfx[t4]     = base2;
      sh.f.pfx[t4 + 1] = base2 + h0;
      sh.f.pfx[t4 + 2] = base2 + h0 + h1;
      sh.f.pfx[t4 + 3] = base2 + h0 + h1 + h2;
    }
    __syncthreads();
    // scatter into bucket-sorted keys2 (pfx becomes running insert ptr)
    if ((u32)tid < m)        { u32 p = atomicAdd(&sh.f.pfx[ba], 1u); sh.f.keys2[p] = k0a; }
    if ((u32)tid + 1024 < m) { u32 p = atomicAdd(&sh.f.pfx[bb], 1u); sh.f.keys2[p] = k0b; }
    __syncthreads();
    // exact rank = bucket_start + within-bucket count of greater keys; emit
    auto emit = [&](u64 k0, int bkt) {
      u32 endq = sh.f.pfx[bkt];            // after scatter: start + size
      u32 startq = endq - sh.f.hist[bkt];
      u32 r = startq;
      for (u32 j = startq; j < endq; ++j) r += (sh.f.keys2[j] > k0) ? 1u : 0u;
      if (r < TOPK) {
        u32 hi = (u32)(k0 >> 32);
        cand_s[obase + r] = __uint_as_float(hi);
        u32 e = ~((u32)k0);
        cand_t[obase + r] = ((u32)l << 19) | (e & 0x7FFFFu);
        cand_box[obase + r] = decode_box(lp, b, l, e);
        if (r == TOPK - 1) s_last = hi;
      }
    };
    if ((u32)tid < m)        emit(k0a, ba);
    if ((u32)tid + 1024 < m) emit(k0b, bb);
    __syncthreads();
    // guard: rank-999 must beat the filter boundary by >64 ulps
    u32 bits_tau = __float_as_uint(sigmoid_ref(c_tau[l]));
    if ((int)cnt != Nsc && !(s_last > bits_tau + 64u)) fast = false;  // block-uniform
  }
  if (fast) return;

  // ---- fallback (never taken for this input; exact for any input) ----
  const float* cls = cp.p[l] + (size_t)b * Nsc;
  __syncthreads();
  for (int i = tid; i < NBINS; i += 1024) sh.histfb[i] = 0;
  if (tid == 0) s_cnt = 0;
  __syncthreads();
  for (int i = tid; i < Nsc; i += 1024) {
    float s = sigmoid_ref(cls[i]);
    atomicAdd(&sh.histfb[__float_as_uint(s) >> 16], 1u);
  }
  __syncthreads();
  { u32 a = 0; for (int j = 0; j < 16; ++j) a += sh.histfb[tid * 16 + j]; part[tid] = a; }
  __syncthreads();
  if (tid == 0) {
    u32 cum = 0; int cut = 0;
    for (int ch = 1023; ch >= 0; --ch) {
      if (cum + part[ch] >= TOPK) {
        u32 cc = cum;
        for (int bin = ch * 16 + 15;; --bin) { cc += sh.histfb[bin]; if (cc >= TOPK) { cut = bin; break; } }
        break;
      }
      cum += part[ch];
    }
    s_cut = cut;
  }
  __syncthreads();
  int cut = s_cut;
  __syncthreads();                 // hist reads done before keys overwrite
  for (int i = tid; i < Nsc; i += 1024) {
    float s = sigmoid_ref(cls[i]);
    u32 bits = __float_as_uint(s);
    bool selp = (int)(bits >> 16) >= cut;
    u64 mk = __ballot((int)selp);
    if (selp) {
      int ldr = __builtin_ctzll(mk);
      u32 pos0 = 0;
      if (lane == ldr) pos0 = atomicAdd(&s_cnt, (u32)__popcll(mk));
      pos0 = (u32)__shfl((int)pos0, ldr);
      u32 pos = pos0 + (u32)__popcll(mk & lowm);
      if (pos < CAP) {
        int ch = i >> lg2;
        int loc = i & (Nloc - 1);
        u32 e = (u32)(loc * NCH + ch);
        sh.keysfb[pos] = ((u64)bits << 32) | (u32)(~e);
      }
    }
  }
  __syncthreads();
  u32 m2 = s_cnt; if (m2 > CAP) m2 = CAP;
  for (u32 i = tid; i < m2; i += 1024) {
    u64 k0 = sh.keysfb[i];
    u32 r = 0;
    #pragma unroll 8
    for (u32 j = 0; j < m2; ++j) r += (sh.keysfb[j] > k0) ? 1u : 0u;
    if (r < TOPK) {
      cand_s[obase + r] = __uint_as_float((u32)(k0 >> 32));
      u32 e = ~((u32)k0);
      cand_t[obase + r] = ((u32)l << 19) | (e & 0x7FFFFu);
      cand_box[obase + r] = decode_box(lp, b, l, e);
    }
  }
  for (u32 r = m2 + tid; r < TOPK; r += 1024) {
    cand_s[obase + r] = -1.0f;
    cand_t[obase + r] = ((u32)l << 19) | r;
    cand_box[obase + r] = make_float4(0.f, 0.f, 0.f, 0.f);
  }
}

// IoU > thresh predicate — identical _rn sequence as reference; div only when inter>0.
__device__ __forceinline__ bool iou_gt4(float4 p, float pa, float4 q, float qa) {
  float ltx = fmaxf(p.x, q.x), lty = fmaxf(p.y, q.y);
  float rx  = fminf(p.z, q.z), ry  = fminf(p.w, q.w);
  float ww = fmaxf(__fsub_rn(rx, ltx), 0.0f);
  float hh = fmaxf(__fsub_rn(ry, lty), 0.0f);
  float inter = __fmul_rn(ww, hh);
  bool res = false;
  if (inter > 0.0f) {
    float denom = fmaxf(__fsub_rn(__fadd_rn(pa, qa), inter), 1e-7f);
    res = __fdiv_rn(inter, denom) > NMS_TH;
  }
  return res;
}
__device__ __forceinline__ float area_rn(float4 p) {
  return __fmul_rn(__fsub_rn(p.z, p.x), __fsub_rn(p.w, p.y));
}

// ---- K3 (fused grank+mask+detect, one block per image) ----
// rank all 5000 candidates (binary searches over the 5 desc-sorted LDS lists),
// scatter rank<512 offset-boxes to LDS (tail to global for the exact fallback),
// build the 512x512 suppression matrix in-LDS with the conflict-free wave-uniform
// column-word schedule, thread-0 sparse greedy, append, emit.
__global__ __launch_bounds__(1024)
void k_fused(const float* __restrict__ cand_s, const u32* __restrict__ cand_t,
             const float4* __restrict__ cand_box,
             float4* __restrict__ rboxOff, u32* __restrict__ rmeta,
             float* __restrict__ out) {
  __shared__ union {
    u64 keys[NCAND];            // 40 KB (rank phase)
    u64 rows[DCH][DW];          // 32 KB (matrix phase; keys dead after scatter)
  } u;
  __shared__ float4 sb[DCH];    // 8 KB  rank-prefix offset boxes
  __shared__ float  sa[DCH];    // 2 KB
  __shared__ u32    sm[DCH];    // 2 KB  meta
  __shared__ int    vc[NLEV];
  __shared__ u32    nzmap[DCH / 32];
  __shared__ u64    validm[DW], keptm[DW];
  __shared__ float4 kbox[NDET];
  __shared__ float  karea2[NDET];
  __shared__ u32    kmeta[NDET];
  __shared__ float4 cbox[64];
  __shared__ float  carea[64];
  __shared__ u64    supsh[16];
  __shared__ u64    rowsh2[64];
  __shared__ u32    s_nk, s_stop;
  int b = blockIdx.x, tid = threadIdx.x;
  int lane = tid & 63, wid = tid >> 6;

  // ---- phase 1: keys ----
  for (int i = tid; i < NCAND; i += 1024) {
    float s = cand_s[b * NCAND + i];
    u32 t = cand_t[b * NCAND + i];
    u32 hi = (s > SCORE_TH) ? __float_as_uint(s) : 0u;
    u.keys[i] = ((u64)hi << 32) | (u32)(~t);
  }
  if (tid < DCH / 32) nzmap[tid] = 0;
  if (tid == 0) { s_nk = 0; s_stop = 0; }
  __syncthreads();
  if (tid < NLEV) {             // validCnt[L] = first index with hi==0
    const u64* A = u.keys + tid * TOPK;
    int lo = 0, h2 = TOPK;
    while (lo < h2) { int mid = (lo + h2) >> 1; if (A[mid] >> 32) lo = mid + 1; else h2 = mid; }
    vc[tid] = lo;
  }
  __syncthreads();
  // ---- phase 2: rank + scatter (5 candidates per thread) ----
  for (int k5 = 0; k5 < 5; ++k5) {
    int i = tid + k5 * 1024;
    if (i >= NCAND) break;
    u64 k0 = u.keys[i];
    u32 hi = (u32)(k0 >> 32);
    u32 t = ~((u32)k0);
    int seg = i / TOPK;
    int rank;
    u32 cls = 0;
    if (hi) {
      rank = i - seg * TOPK;
      for (int L = 0; L < NLEV; ++L) {
        if (L == seg) continue;
        const u64* A = u.keys + L * TOPK;
        int lo = 0, h2 = TOPK;                  // count of A[j] > k0 (monotone)
        while (lo < h2) { int mid = (lo + h2) >> 1; if (A[mid] > k0) lo = mid + 1; else h2 = mid; }
        rank += lo;
      }
      cls = t & 7u;
    } else {
      int tv = 0, before = 0;
      for (int L = 0; L < NLEV; ++L) { tv += vc[L]; if (L < seg) before += TOPK - vc[L]; }
      rank = tv + before + ((i - seg * TOPK) - vc[seg]);   // distinct, >= totalValid
    }
    float4 v = cand_box[b * NCAND + i];
    float off = __fmul_rn((float)cls, IMGSZ + 1.0f);
    float4 q;
    q.x = __fadd_rn(v.x, off); q.y = __fadd_rn(v.y, off);
    q.z = __fadd_rn(v.z, off); q.w = __fadd_rn(v.w, off);
    u32 meta = hi ? (((u32)i << 8) | cls) : 0xFFFFFFFFu;
    if (rank < DCH) {
      sb[rank] = q; sa[rank] = area_rn(q); sm[rank] = meta;
    } else {
      rboxOff[b * NCAND + rank] = q;
      rmeta[b * NCAND + rank] = meta;
    }
  }
  __syncthreads();             // keys dead from here; u.rows aliases them
  // ---- phase 3: suppression matrix in LDS (conflict-free schedule) ----
  // wave wv: row-block rb = wv>>1 (rows rb*64+lane), words w = (wv&1), +2, +4, +6.
  {
    int rb = wid >> 1, half = wid & 1;
    int r = rb * 64 + lane;
    float4 qr = sb[r]; float ar = sa[r];
    bool any = false;
    for (int w = half; w < DW; w += 2) {
      u64 bits = 0;
      if (w >= rb) {
        int j0 = w * 64;
        if (w > rb) {
          #pragma unroll 4
          for (int jc = 0; jc < 64; ++jc)
            if (iou_gt4(qr, ar, sb[j0 + jc], sa[j0 + jc])) bits |= 1ull << jc;
        } else {                            // diagonal word: guard j > r
          #pragma unroll 4
          for (int jc = 0; jc < 64; ++jc) {
            int j = j0 + jc;
            if (j > r && iou_gt4(qr, ar, sb[j], sa[j])) bits |= 1ull << jc;
          }
        }
      }
      u.rows[r][w] = bits;
      any |= (bits != 0);
    }
    if (any) atomicOr(&nzmap[r >> 5], 1u << (r & 31));
  }
  if (tid < DCH) {
    u64 bv = __ballot((int)(sm[tid] != 0xFFFFFFFFu));
    if (lane == 0) validm[tid >> 6] = bv;
  }
  __syncthreads();
  // ---- phase 4: thread-0 sparse greedy over nonzero rows (rank order) ----
  if (tid == 0) {
    u64 kw[DW];
    #pragma unroll
    for (int w = 0; w < DW; ++w) kw[w] = validm[w];
    for (int mw = 0; mw < DCH / 32; ++mw) {
      u32 nzw = nzmap[mw];
      while (nzw) {
        int bit = __builtin_ctz(nzw); nzw &= nzw - 1;
        int i = mw * 32 + bit;
        if ((kw[i >> 6] >> (i & 63)) & 1ull) {
          #pragma unroll
          for (int v = 0; v < DW; ++v) kw[v] &= ~u.rows[i][v];
        }
      }
    }
    #pragma unroll
    for (int w = 0; w < DW; ++w) keptm[w] = kw[w];
  }
  __syncthreads();
  // ---- phase 5: append kept (rank order, cap NDET) ----
  if (tid < DCH) {
    int w = tid >> 6;
    u64 kwv = keptm[w];
    if ((kwv >> (tid & 63)) & 1ull) {
      u32 pre = 0;
      for (int v = 0; v < w; ++v) pre += (u32)__popcll(keptm[v]);
      pre += (u32)__popcll(kwv & ((1ull << (tid & 63)) - 1ull));
      if (pre < NDET) { kbox[pre] = sb[tid]; karea2[pre] = sa[tid]; kmeta[pre] = sm[tid]; }
    }
  }
  __syncthreads();
  if (tid == 0) {
    u32 add = 0, nvalid = 0;
    #pragma unroll
    for (int w = 0; w < DW; ++w) { add += (u32)__popcll(keptm[w]); nvalid += (u32)__popcll(validm[w]); }
    u32 nn = add; if (nn > NDET) nn = NDET;
    s_nk = nn;
    if (nn >= (u32)NDET || nvalid < (u32)DCH) s_stop = 1;
  }
  __syncthreads();

  // ---- fallback for ranks >= DCH (rare; exact greedy, single combined kept list) ----
  int n = (int)s_nk;
  for (int base = DCH; base < NCAND && !s_stop; base += 64) {
    int ci = base + lane;
    u32 meta = (ci < NCAND) ? rmeta[b * NCAND + ci] : 0xFFFFFFFFu;
    bool valid = meta != 0xFFFFFFFFu;
    float4 q = (ci < NCAND) ? rboxOff[b * NCAND + ci] : make_float4(0.f, 0.f, 0.f, 0.f);
    float aq = area_rn(q);
    if (wid == 0) { cbox[lane] = q; carea[lane] = aq; }
    bool sup = false;
    if (valid) for (int k = wid; k < n; k += 16) sup = sup | iou_gt4(kbox[k], karea2[k], q, aq);
    u64 bal = __ballot((int)sup);
    if (lane == 0) supsh[wid] = bal;
    __syncthreads();
    if (wid == 0) {
      u64 supm = 0;
      for (int w = 0; w < 16; ++w) supm |= supsh[w];
      u64 vm = __ballot((int)valid);
      u64 pending = vm & ~supm;
      u64 row = 0;
      if ((pending >> lane) & 1ull) {
        u64 mine = pending & ~((2ull << lane) - 1ull);
        while (mine) {
          int j = __builtin_ctzll(mine); mine &= mine - 1ull;
          if (iou_gt4(q, aq, cbox[j], carea[j])) row |= (1ull << j);
        }
      }
      rowsh2[lane] = row;
      u64 nz = __ballot((int)(row != 0ull));
      bool done = false;
      u64 rem = pending;
      while (rem) {
        int r = __builtin_ctzll(rem); rem &= rem - 1ull;
        if (lane == r) { kmeta[n] = meta; kbox[n] = q; karea2[n] = aq; }
        ++n;
        if (n == NDET) { done = true; break; }
        if ((nz >> r) & 1ull) rem &= ~rowsh2[r];
      }
      if (__any((int)(!valid))) done = true;
      if (lane == 0) { s_nk = (u32)n; s_stop = done ? 1u : 0u; }
    }
    __syncthreads();
    n = (int)s_nk;
  }

  // ---- emit: boxes [B,300,4] ++ scores [B,300] ++ labels [B,300] ----
  int nf = (int)s_nk;
  for (int k = tid; k < NDET; k += 1024) {
    float bx0 = 0.f, bx1 = 0.f, bx2 = 0.f, bx3 = 0.f, sc = 0.f, lb = -1.0f;
    if (k < nf) {
      u32 m = kmeta[k];
      int io = (int)(m >> 8);
      float4 v = cand_box[b * NCAND + io];
      bx0 = v.x; bx1 = v.y; bx2 = v.z; bx3 = v.w;
      sc = cand_s[b * NCAND + io];
      lb = (float)(m & 0xFFu);
    }
    int idx = b * NDET + k;
    out[(size_t)idx * 4 + 0] = bx0;
    out[(size_t)idx * 4 + 1] = bx1;
    out[(size_t)idx * 4 + 2] = bx2;
    out[(size_t)idx * 4 + 3] = bx3;
    out[NB * NDET * 4 + idx] = sc;
    out[NB * NDET * 5 + idx] = lb;
  }
}

extern "C" void kernel_launch(void* const* d_in, const int* in_sizes, int n_in,
                              void* d_out, int out_size, void* d_ws, size_t ws_size,
                              hipStream_t stream) {
  const float* cls[NLEV]; const float* reg[NLEV]; const float* anc[NLEV];
  bool dict_order = (n_in >= 2) && (in_sizes[1] == 4 * NREGCH * 64 * 64);
  for (int l = 0; l < NLEV; ++l) {
    if (dict_order) {
      cls[l] = (const float*)d_in[3 * l + 0];
      reg[l] = (const float*)d_in[3 * l + 1];
      anc[l] = (const float*)d_in[3 * l + 2];
    } else {
      cls[l] = (const float*)d_in[l];
      reg[l] = (const float*)d_in[NLEV + l];
      anc[l] = (const float*)d_in[2 * NLEV + l];
    }
  }

  char* ws = (char*)d_ws;
  size_t off = 0;
  auto alloc = [&](size_t bytes) -> void* {
    void* p = ws + off;
    off = (off + bytes + 255) & ~(size_t)255;
    return p;
  };
  u32*    bcnt     = (u32*)   alloc((size_t)NB * NCHUNK_IMG * 4);
  u64*    sel      = (u64*)   alloc(20ULL * CAP * 8);
  float*  cand_s   = (float*) alloc((size_t)NB * NCAND * 4);
  u32*    cand_t   = (u32*)   alloc((size_t)NB * NCAND * 4);
  float4* cand_box = (float4*)alloc((size_t)NB * NCAND * 16);
  float4* rboxOff  = (float4*)alloc((size_t)NB * NCAND * 16);
  u32*    rmeta    = (u32*)   alloc((size_t)NB * NCAND * 4);
  (void)ws_size; (void)out_size;

  ClsPtrs cp;
  for (int l = 0; l < NLEV; ++l) cp.p[l] = cls[l];
  LevelPtrs lp;
  for (int l = 0; l < NLEV; ++l) { lp.reg[l] = reg[l]; lp.anc[l] = anc[l]; }

  k_filter<<<NB * NCHUNK_IMG, 256, 0, stream>>>(cp, bcnt, sel);
  k_rank<<<NB * NLEV, 1024, 0, stream>>>(cp, lp, bcnt, sel, cand_s, cand_t, cand_box);
  k_fused<<<NB, 1024, 0, stream>>>(cand_s, cand_t, cand_box, rboxOff, rmeta, (float*)d_out);
}

// Round 19
// 60.040 us; speedup vs baseline: 1.3518x; 1.3518x over previous
//
#include <hip/hip_runtime.h>
#include <stdint.h>
#include <stddef.h>

typedef unsigned int u32;
typedef unsigned long long u64;
typedef unsigned short u16;
typedef unsigned char u8;

#define NB 4
#define NLEV 5
#define NCH 72      // A*C = 9*8
#define NREGCH 36   // A*4
#define TOPK 1000
#define NCAND 5000  // NLEV*TOPK
#define NDET 300
#define NBINS 16384       // fallback hist: sigmoid float bits >> 16
#define RNB 4096          // counting-rank buckets (fast path)
#define CAP 8192          // per-(b,level) filtered-candidate buffer
#define FASTCAP 2048      // fast-path key limit (2 keys/thread @ 1024 thr)
#define CHUNK 8192
#define NCHUNK_IMG 50     // 36+9+3+1+1
#define DCH 512           // NMS rank-prefix chunk
#define DW 8              // u64 words per suppression row
#define IMGSZ 512.0f
#define SCORE_TH 0.05f
#define NMS_TH 0.5f
#define BBOX_CLIP_F 4.135166556742356f

__constant__ int c_f[NLEV]    = {64, 32, 16, 8, 4};
__constant__ int c_Nloc[NLEV] = {4096, 1024, 256, 64, 16};
__constant__ int c_lg2[NLEV]  = {12, 10, 8, 6, 4};
// logit prefilter thresholds: ~1400 expected survivors at levels 0-3 (10-sigma
// margins vs both TOPK=1000 and FASTCAP=2048); level 4 unfiltered (1152 total).
__constant__ float c_tau[NLEV] = {2.594f, 2.075f, 1.433f, 0.513f, -1e30f};
// counting-rank bucket shifts: (0x3F800000 - bits(sigmoid(tau))) >> shift < RNB
__constant__ int c_rshift[NLEV] = {10, 10, 11, 12, 18};
// per-level chunk layout inside a group's CAP region (atomic-free k_filter)
__constant__ int c_nch[NLEV]  = {36, 9, 3, 1, 1};
__constant__ int c_clo[NLEV]  = {0, 36, 45, 48, 49};
__constant__ int c_ccap[NLEV] = {227, 910, 2730, 8192, 8192};  // CAP/nch

// ---- XLA-CPU-style sigmoid: logistic(x) = 0.5 + 0.5*tanh(0.5*x), fast-tanh poly, no FMA ----
__device__ __forceinline__ float xla_tanh_f32(float x) {
  float ax = fabsf(x);
  float xc = fminf(fmaxf(x, -7.90531110763549805f), 7.90531110763549805f);
  float x2 = __fmul_rn(xc, xc);
  float p = -2.76076847742355e-16f;
  p = __fadd_rn(__fmul_rn(x2, p), 2.00018790482477e-13f);
  p = __fadd_rn(__fmul_rn(x2, p), -8.60467152213735e-11f);
  p = __fadd_rn(__fmul_rn(x2, p), 5.12229709037114e-08f);
  p = __fadd_rn(__fmul_rn(x2, p), 1.48572235717979e-05f);
  p = __fadd_rn(__fmul_rn(x2, p), 6.37261928875436e-04f);
  p = __fadd_rn(__fmul_rn(x2, p), 4.89352455891786e-03f);
  float num = __fmul_rn(xc, p);
  float q = 1.19825839466702e-06f;
  q = __fadd_rn(__fmul_rn(x2, q), 1.18534705686654e-04f);
  q = __fadd_rn(__fmul_rn(x2, q), 2.26843463243900e-03f);
  q = __fadd_rn(__fmul_rn(x2, q), 4.89352518554385e-03f);
  float r = __fdiv_rn(num, q);
  return (ax < 0.0004f) ? x : r;
}
__device__ __forceinline__ float sigmoid_ref(float x) {
  return __fadd_rn(0.5f, __fmul_rn(0.5f, xla_tanh_f32(__fmul_rn(0.5f, x))));
}

struct ClsPtrs { const float* p[NLEV]; };
struct LevelPtrs { const float* reg[NLEV]; const float* anc[NLEV]; };

__device__ __forceinline__ void chunk_map(int bid, int& b, int& level, int& chunk) {
  b = bid / NCHUNK_IMG;
  int cid = bid % NCHUNK_IMG;
  if      (cid < 36) { level = 0; chunk = cid; }
  else if (cid < 45) { level = 1; chunk = cid - 36; }
  else if (cid < 48) { level = 2; chunk = cid - 45; }
  else if (cid < 49) { level = 3; chunk = cid - 48; }
  else               { level = 4; chunk = cid - 49; }
}

// exact BoxCoder decode + clip (identical _rn sequence as all passing rounds)
__device__ __forceinline__ float4 decode_box(const LevelPtrs& lp, int b, int lv, u32 e) {
  u32 anc = e >> 3;              // loc*9 + a
  int a = (int)(anc % 9u);
  int loc = (int)(anc / 9u);
  int f = c_f[lv];
  int Nloc = f * f;
  const float* rp = lp.reg[lv];
  const float* ap = lp.anc[lv] + (size_t)anc * 4;
  float r0 = rp[((size_t)b * NREGCH + (a * 4 + 0)) * Nloc + loc];
  float r1 = rp[((size_t)b * NREGCH + (a * 4 + 1)) * Nloc + loc];
  float r2 = rp[((size_t)b * NREGCH + (a * 4 + 2)) * Nloc + loc];
  float r3 = rp[((size_t)b * NREGCH + (a * 4 + 3)) * Nloc + loc];
  float a0 = ap[0], a1 = ap[1], a2 = ap[2], a3 = ap[3];
  float aw = __fsub_rn(a2, a0);
  float ah = __fsub_rn(a3, a1);
  float acx = __fadd_rn(a0, __fmul_rn(0.5f, aw));
  float acy = __fadd_rn(a1, __fmul_rn(0.5f, ah));
  float dw = fminf(r2, BBOX_CLIP_F);
  float dh = fminf(r3, BBOX_CLIP_F);
  float pcx = __fadd_rn(__fmul_rn(r0, aw), acx);
  float pcy = __fadd_rn(__fmul_rn(r1, ah), acy);
  float pw = __fmul_rn(expf(dw), aw);
  float ph = __fmul_rn(expf(dh), ah);
  float hx = __fmul_rn(0.5f, pw);
  float hy = __fmul_rn(0.5f, ph);
  float4 v;
  v.x = fminf(fmaxf(__fsub_rn(pcx, hx), 0.0f), IMGSZ);
  v.y = fminf(fmaxf(__fsub_rn(pcy, hy), 0.0f), IMGSZ);
  v.z = fminf(fmaxf(__fadd_rn(pcx, hx), 0.0f), IMGSZ);
  v.w = fminf(fmaxf(__fadd_rn(pcy, hy), 0.0f), IMGSZ);
  return v;
}

// ---- K1: logit-prefilter, ATOMIC-FREE: per-chunk region writes + per-block count ----
__global__ __launch_bounds__(256)
void k_filter(ClsPtrs cp, u32* __restrict__ bcnt, u64* __restrict__ sel) {
  int b, level, chunk;
  chunk_map(blockIdx.x, b, level, chunk);
  int Nloc = c_Nloc[level], lg2 = c_lg2[level];
  int Nsc = Nloc * NCH;
  int g = b * NLEV + level;
  const float* cls = cp.p[level] + (size_t)b * Nsc;
  float tau = c_tau[level];
  int base = chunk * CHUNK;
  int end = base + CHUNK; if (end > Nsc) end = Nsc;
  int wid = threadIdx.x >> 6, lane = threadIdx.x & 63;
  u64 lowm = (1ull << lane) - 1ull;
  __shared__ u32 wcnt[4];
  u32 mycnt = 0;
  for (int i = base + threadIdx.x; i < end; i += 256) {
    u64 mk = __ballot((int)(cls[i] > tau));
    mycnt += (u32)__popcll(mk);
  }
  if (lane == 0) wcnt[wid] = mycnt;
  __syncthreads();
  u32 wbase = 0, tot = 0;
  for (int w = 0; w < 4; ++w) { u32 c = wcnt[w]; if (w < wid) wbase += c; tot += c; }
  if (threadIdx.x == 0) bcnt[blockIdx.x] = tot;   // always written: no memset needed
  if (!tot) return;
  u32 ccap = (u32)c_ccap[level];
  size_t regbase = (size_t)g * CAP + (size_t)chunk * ccap;
  u32 run = 0;
  for (int i = base + threadIdx.x; i < end; i += 256) {
    float x = cls[i];
    bool selp = x > tau;                 // monotone sigmoid => logit-space superset filter
    u64 mk = __ballot((int)selp);
    if (selp) {
      u32 pos = wbase + run + (u32)__popcll(mk & lowm);
      if (pos < ccap) {
        u32 bits = __float_as_uint(sigmoid_ref(x));
        int ch = i >> lg2;
        int loc = i & (Nloc - 1);
        u32 e = (u32)(loc * NCH + ch);   // flat score index ((y*f+x)*9+a)*8+c
        sel[regbase + pos] = ((u64)bits << 32) | (u32)(~e);
      }
    }
    run += (u32)__popcll(mk);
  }
}

// ---- K2: exact top-1000 via LDS counting-rank + fused decode; guarded fast path ----
__global__ __launch_bounds__(1024)
void k_rank(ClsPtrs cp, LevelPtrs lp, const u32* __restrict__ bcnt,
            const u64* __restrict__ sel,
            float* __restrict__ cand_s, u32* __restrict__ cand_t,
            float4* __restrict__ cand_box) {
  __shared__ union {
    struct { u64 keysC[FASTCAP]; u64 keys2[FASTCAP]; u32 hist[RNB]; u32 pfx[RNB]; } f; // 64 KB
    u32 histfb[NBINS];                                              // 64 KB
    u64 keysfb[CAP];                                                // 64 KB
  } sh;
  __shared__ u32 part[1024];
  __shared__ u32 ccnt[36];
  __shared__ u32 cbase[37];
  __shared__ u32 s_ovf;
  __shared__ u32 s_last;
  __shared__ u32 s_cnt;
  __shared__ int s_cut;
  int g = blockIdx.x;
  int b = g / NLEV, l = g % NLEV;
  int Nloc = c_Nloc[l], lg2 = c_lg2[l];
  int Nsc = Nloc * NCH;
  int tid = threadIdx.x;
  int lane = tid & 63;
  u64 lowm = (1ull << lane) - 1ull;
  int obase = b * NCAND + l * TOPK;
  int nch = c_nch[l], clo = c_clo[l];
  u32 ccap = (u32)c_ccap[l];
  if (tid < nch) ccnt[tid] = bcnt[b * NCHUNK_IMG + clo + tid];
  __syncthreads();
  if (tid == 0) {
    u32 a = 0, ovf = 0;
    for (int c = 0; c < nch; ++c) { cbase[c] = a; a += ccnt[c]; if (ccnt[c] > ccap) ovf = 1; }
    cbase[nch] = a; s_ovf = ovf;
  }
  __syncthreads();
  u32 cnt = cbase[nch];
  bool fast = (cnt >= TOPK) && (cnt <= FASTCAP) && !s_ovf;
  if (fast) {
    u32 m = cnt;
    int shift = c_rshift[l];
    // PARALLEL compaction: each element binary-searches its chunk via cbase
    for (u32 i = tid; i < m; i += 1024) {
      int lo = 0, h2 = nch - 1;
      while (lo < h2) { int mid = (lo + h2 + 1) >> 1; if (cbase[mid] <= i) lo = mid; else h2 = mid - 1; }
      sh.f.keysC[i] = sel[(size_t)g * CAP + (size_t)lo * ccap + (i - cbase[lo])];
    }
    for (int i = tid; i < RNB; i += 1024) sh.f.hist[i] = 0;
    if (tid == 0) s_last = 0;
    __syncthreads();
    u64 k0a = ((u32)tid < m)        ? sh.f.keysC[tid]        : 0ULL;
    u64 k0b = ((u32)tid + 1024 < m) ? sh.f.keysC[tid + 1024] : 0ULL;
    // bucket: monotone DECREASING in key; clamp handles tails exactly
    auto bkt_of = [&](u64 k) -> int {
      int d = (int)0x3F800000 - (int)(u32)(k >> 32);
      if (d < 0) d = 0;
      int bq = d >> shift;
      return bq > RNB - 1 ? RNB - 1 : bq;
    };
    int ba = bkt_of(k0a), bb = bkt_of(k0b);
    if ((u32)tid < m)        atomicAdd(&sh.f.hist[ba], 1u);
    if ((u32)tid + 1024 < m) atomicAdd(&sh.f.hist[bb], 1u);
    __syncthreads();
    // exclusive prefix scan of hist[RNB] -> pfx
    {
      int t4 = tid * 4;
      u32 h0 = sh.f.hist[t4], h1 = sh.f.hist[t4 + 1], h2 = sh.f.hist[t4 + 2], h3 = sh.f.hist[t4 + 3];
      u32 s4 = h0 + h1 + h2 + h3;
      u32 x = s4;
      for (int d = 1; d < 64; d <<= 1) { u32 y = __shfl_up(x, d); if (lane >= d) x += y; }
      if (lane == 63) part[tid >> 6] = x;
      __syncthreads();
      if (tid == 0) { u32 a = 0; for (int w = 0; w < 16; ++w) { u32 c = part[w]; part[w] = a; a += c; } }
      __syncthreads();
      u32 base2 = part[tid >> 6] + (x - s4);
      sh.f.pfx[t4]     = base2;
      sh.f.pfx[t4 + 1] = base2 + h0;
      sh.f.pfx[t4 + 2] = base2 + h0 + h1;
      sh.f.pfx[t4 + 3] = base2 + h0 + h1 + h2;
    }
    __syncthreads();
    // scatter into bucket-sorted keys2 (pfx becomes running insert ptr)
    if ((u32)tid < m)        { u32 p = atomicAdd(&sh.f.pfx[ba], 1u); sh.f.keys2[p] = k0a; }
    if ((u32)tid + 1024 < m) { u32 p = atomicAdd(&sh.f.pfx[bb], 1u); sh.f.keys2[p] = k0b; }
    __syncthreads();
    // exact rank = bucket_start + within-bucket count of greater keys; emit
    auto emit = [&](u64 k0, int bkt) {
      u32 endq = sh.f.pfx[bkt];            // after scatter: start + size
      u32 startq = endq - sh.f.hist[bkt];
      u32 r = startq;
      for (u32 j = startq; j < endq; ++j) r += (sh.f.keys2[j] > k0) ? 1u : 0u;
      if (r < TOPK) {
        u32 hi = (u32)(k0 >> 32);
        cand_s[obase + r] = __uint_as_float(hi);
        u32 e = ~((u32)k0);
        cand_t[obase + r] = ((u32)l << 19) | (e & 0x7FFFFu);
        cand_box[obase + r] = decode_box(lp, b, l, e);
        if (r == TOPK - 1) s_last = hi;
      }
    };
    if ((u32)tid < m)        emit(k0a, ba);
    if ((u32)tid + 1024 < m) emit(k0b, bb);
    __syncthreads();
    // guard: rank-999 must beat the filter boundary by >64 ulps
    u32 bits_tau = __float_as_uint(sigmoid_ref(c_tau[l]));
    if ((int)cnt != Nsc && !(s_last > bits_tau + 64u)) fast = false;  // block-uniform
  }
  if (fast) return;

  // ---- fallback (never taken for this input; exact for any input) ----
  const float* cls = cp.p[l] + (size_t)b * Nsc;
  __syncthreads();
  for (int i = tid; i < NBINS; i += 1024) sh.histfb[i] = 0;
  if (tid == 0) s_cnt = 0;
  __syncthreads();
  for (int i = tid; i < Nsc; i += 1024) {
    float s = sigmoid_ref(cls[i]);
    atomicAdd(&sh.histfb[__float_as_uint(s) >> 16], 1u);
  }
  __syncthreads();
  { u32 a = 0; for (int j = 0; j < 16; ++j) a += sh.histfb[tid * 16 + j]; part[tid] = a; }
  __syncthreads();
  if (tid == 0) {
    u32 cum = 0; int cut = 0;
    for (int ch = 1023; ch >= 0; --ch) {
      if (cum + part[ch] >= TOPK) {
        u32 cc = cum;
        for (int bin = ch * 16 + 15;; --bin) { cc += sh.histfb[bin]; if (cc >= TOPK) { cut = bin; break; } }
        break;
      }
      cum += part[ch];
    }
    s_cut = cut;
  }
  __syncthreads();
  int cut = s_cut;
  __syncthreads();                 // hist reads done before keys overwrite
  for (int i = tid; i < Nsc; i += 1024) {
    float s = sigmoid_ref(cls[i]);
    u32 bits = __float_as_uint(s);
    bool selp = (int)(bits >> 16) >= cut;
    u64 mk = __ballot((int)selp);
    if (selp) {
      int ldr = __builtin_ctzll(mk);
      u32 pos0 = 0;
      if (lane == ldr) pos0 = atomicAdd(&s_cnt, (u32)__popcll(mk));
      pos0 = (u32)__shfl((int)pos0, ldr);
      u32 pos = pos0 + (u32)__popcll(mk & lowm);
      if (pos < CAP) {
        int ch = i >> lg2;
        int loc = i & (Nloc - 1);
        u32 e = (u32)(loc * NCH + ch);
        sh.keysfb[pos] = ((u64)bits << 32) | (u32)(~e);
      }
    }
  }
  __syncthreads();
  u32 m2 = s_cnt; if (m2 > CAP) m2 = CAP;
  for (u32 i = tid; i < m2; i += 1024) {
    u64 k0 = sh.keysfb[i];
    u32 r = 0;
    #pragma unroll 8
    for (u32 j = 0; j < m2; ++j) r += (sh.keysfb[j] > k0) ? 1u : 0u;
    if (r < TOPK) {
      cand_s[obase + r] = __uint_as_float((u32)(k0 >> 32));
      u32 e = ~((u32)k0);
      cand_t[obase + r] = ((u32)l << 19) | (e & 0x7FFFFu);
      cand_box[obase + r] = decode_box(lp, b, l, e);
    }
  }
  for (u32 r = m2 + tid; r < TOPK; r += 1024) {
    cand_s[obase + r] = -1.0f;
    cand_t[obase + r] = ((u32)l << 19) | r;
    cand_box[obase + r] = make_float4(0.f, 0.f, 0.f, 0.f);
  }
}

// ---- K3: global rank per candidate (wide: 5 blocks/image); deterministic
//      invalid ranks (no atomics); scatter rank-ordered offset-box + meta. ----
__global__ __launch_bounds__(1024)
void k_grank(const float* __restrict__ cand_s, const u32* __restrict__ cand_t,
             const float4* __restrict__ cand_box,
             float4* __restrict__ rboxOff, u32* __restrict__ rmeta) {
  __shared__ u64 keys[NCAND];   // 40 KB
  __shared__ int vc[NLEV];
  int b = blockIdx.y;
  int seg = blockIdx.x;         // level list 0..4
  int tid = threadIdx.x;
  for (int i = tid; i < NCAND; i += 1024) {
    float s = cand_s[b * NCAND + i];
    u32 t = cand_t[b * NCAND + i];
    u32 hi = (s > SCORE_TH) ? __float_as_uint(s) : 0u;
    keys[i] = ((u64)hi << 32) | (u32)(~t);
  }
  __syncthreads();
  if (tid < NLEV) {             // validCnt[L] = first index with hi==0
    const u64* A = keys + tid * TOPK;
    int lo = 0, h2 = TOPK;
    while (lo < h2) { int mid = (lo + h2) >> 1; if (A[mid] >> 32) lo = mid + 1; else h2 = mid; }
    vc[tid] = lo;
  }
  __syncthreads();
  if (tid >= TOPK) return;
  int i = seg * TOPK + tid;
  u64 k0 = keys[i];
  u32 hi = (u32)(k0 >> 32);
  u32 t = ~((u32)k0);
  int rank;
  u32 cls = 0;
  if (hi) {
    rank = tid;                               // own list: earlier entries greater
    for (int L = 0; L < NLEV; ++L) {
      if (L == seg) continue;
      const u64* A = keys + L * TOPK;
      int lo = 0, h2 = TOPK;                  // count of A[j] > k0 (monotone)
      while (lo < h2) { int mid = (lo + h2) >> 1; if (A[mid] > k0) lo = mid + 1; else h2 = mid; }
      rank += lo;
    }
    cls = t & 7u;
  } else {
    int tv = 0, before = 0;
    for (int L = 0; L < NLEV; ++L) { tv += vc[L]; if (L < seg) before += TOPK - vc[L]; }
    rank = tv + before + (tid - vc[seg]);     // distinct, all >= totalValid
  }
  float4 v = cand_box[b * NCAND + i];
  float off = __fmul_rn((float)cls, IMGSZ + 1.0f);
  float4 q;
  q.x = __fadd_rn(v.x, off); q.y = __fadd_rn(v.y, off);
  q.z = __fadd_rn(v.z, off); q.w = __fadd_rn(v.w, off);
  rboxOff[b * NCAND + rank] = q;
  rmeta[b * NCAND + rank] = hi ? (((u32)i << 8) | cls) : 0xFFFFFFFFu;
}

// IoU > thresh predicate — identical _rn sequence as reference; div only when inter>0.
__device__ __forceinline__ bool iou_gt4(float4 p, float pa, float4 q, float qa) {
  float ltx = fmaxf(p.x, q.x), lty = fmaxf(p.y, q.y);
  float rx  = fminf(p.z, q.z), ry  = fminf(p.w, q.w);
  float ww = fmaxf(__fsub_rn(rx, ltx), 0.0f);
  float hh = fmaxf(__fsub_rn(ry, lty), 0.0f);
  float inter = __fmul_rn(ww, hh);
  bool res = false;
  if (inter > 0.0f) {
    float denom = fmaxf(__fsub_rn(__fadd_rn(pa, qa), inter), 1e-7f);
    res = __fdiv_rn(inter, denom) > NMS_TH;
  }
  return res;
}
__device__ __forceinline__ float area_rn(float4 p) {
  return __fmul_rn(__fsub_rn(p.z, p.x), __fsub_rn(p.w, p.y));
}

// ---- K4: wide suppression-matrix build over the 512-rank prefix ----
__global__ __launch_bounds__(256)
void k_mask(const float4* __restrict__ rboxOff, u64* __restrict__ rowsG) {
  __shared__ float4 sb[DCH];   // 8 KB offset boxes
  __shared__ float  sa[DCH];   // 2 KB areas
  int b = blockIdx.y, rb = blockIdx.x;   // row-block: rows rb*64 .. rb*64+63
  int tid = threadIdx.x;
  for (int i = tid; i < DCH; i += 256) {
    float4 q = rboxOff[b * NCAND + i];
    sb[i] = q; sa[i] = area_rn(q);
  }
  __syncthreads();
  int lane = tid & 63, wv = tid >> 6;
  int r = rb * 64 + lane;
  float4 qr = sb[r]; float ar = sa[r];
  u64* rowp = rowsG + ((size_t)b * DCH + r) * DW;
  for (int w = wv; w < rb; w += 4) rowp[w] = 0;
  for (int w = rb + wv; w < DW; w += 4) {
    u64 bits = 0;
    int j0 = w * 64;
    if (w > rb) {
      #pragma unroll 4
      for (int jc = 0; jc < 64; ++jc)
        if (iou_gt4(qr, ar, sb[j0 + jc], sa[j0 + jc])) bits |= 1ull << jc;
    } else {                                // diagonal word: guard j > r
      #pragma unroll 4
      for (int jc = 0; jc < 64; ++jc) {
        int j = j0 + jc;
        if (j > r && iou_gt4(qr, ar, sb[j], sa[j])) bits |= 1ull << jc;
      }
    }
    rowp[w] = bits;
  }
}

// ---- K5: scalar greedy over precomputed matrix + append + emit; exact fallback ----
__global__ __launch_bounds__(1024)
void k_detect(const float* __restrict__ cand_s, const float4* __restrict__ cand_box,
              const float4* __restrict__ rboxOff, const u32* __restrict__ rmeta,
              const u64* __restrict__ rowsG, float* __restrict__ out) {
  __shared__ u64 rows[DCH][DW];     // 32 KB
  __shared__ u32 sm[DCH];           //  2 KB
  __shared__ u32 nzmap[DCH / 32];
  __shared__ u64 validm[DW], keptm[DW];
  __shared__ float4 kbox[NDET];     // kept offset boxes (fallback phase A)
  __shared__ float  karea2[NDET];
  __shared__ u32    kmeta[NDET];
  __shared__ float4 cbox[64];
  __shared__ float  carea[64];
  __shared__ u64    supsh[16];
  __shared__ u64    rowsh2[64];
  __shared__ u32 s_nk, s_stop;
  int b = blockIdx.x, tid = threadIdx.x;
  int lane = tid & 63, wid = tid >> 6;
  if (tid < DCH / 32) nzmap[tid] = 0;
  if (tid == 0) { s_nk = 0; s_stop = 0; }
  __syncthreads();
  for (int k = tid; k < DCH * DW; k += 1024) {
    u64 v = rowsG[(size_t)b * DCH * DW + k];
    ((u64*)rows)[k] = v;
    if (v) atomicOr(&nzmap[(k / DW) >> 5], 1u << ((k / DW) & 31));
  }
  if (tid < DCH) sm[tid] = rmeta[b * NCAND + tid];
  __syncthreads();
  if (tid < DCH) {
    u64 bv = __ballot((int)(sm[tid] != 0xFFFFFFFFu));
    if (lane == 0) validm[tid >> 6] = bv;
  }
  __syncthreads();
  if (tid == 0) {
    u64 kw[DW];
    #pragma unroll
    for (int w = 0; w < DW; ++w) kw[w] = validm[w];
    for (int mw = 0; mw < DCH / 32; ++mw) {
      u32 nzw = nzmap[mw];
      while (nzw) {
        int bit = __builtin_ctz(nzw); nzw &= nzw - 1;
        int i = mw * 32 + bit;
        if ((kw[i >> 6] >> (i & 63)) & 1ull) {
          #pragma unroll
          for (int v = 0; v < DW; ++v) kw[v] &= ~rows[i][v];
        }
      }
    }
    #pragma unroll
    for (int w = 0; w < DW; ++w) keptm[w] = kw[w];
  }
  __syncthreads();
  if (tid < DCH) {
    int w = tid >> 6;
    u64 kwv = keptm[w];
    if ((kwv >> (tid & 63)) & 1ull) {
      u32 pre = 0;
      for (int v = 0; v < w; ++v) pre += (u32)__popcll(keptm[v]);
      pre += (u32)__popcll(kwv & ((1ull << (tid & 63)) - 1ull));
      if (pre < NDET) {
        float4 q = rboxOff[b * NCAND + tid];
        kbox[pre] = q; karea2[pre] = area_rn(q); kmeta[pre] = sm[tid];
      }
    }
  }
  __syncthreads();
  if (tid == 0) {
    u32 add = 0, nvalid = 0;
    #pragma unroll
    for (int w = 0; w < DW; ++w) { add += (u32)__popcll(keptm[w]); nvalid += (u32)__popcll(validm[w]); }
    u32 nn = add; if (nn > NDET) nn = NDET;
    s_nk = nn;
    if (nn >= (u32)NDET || nvalid < (u32)DCH) s_stop = 1;
  }
  __syncthreads();

  // ---- fallback for ranks >= DCH (rare; exact greedy, single combined kept list) ----
  int n = (int)s_nk;
  for (int base = DCH; base < NCAND && !s_stop; base += 64) {
    int ci = base + lane;
    u32 meta = (ci < NCAND) ? rmeta[b * NCAND + ci] : 0xFFFFFFFFu;
    bool valid = meta != 0xFFFFFFFFu;
    float4 q = (ci < NCAND) ? rboxOff[b * NCAND + ci] : make_float4(0.f, 0.f, 0.f, 0.f);
    float aq = area_rn(q);
    if (wid == 0) { cbox[lane] = q; carea[lane] = aq; }
    bool sup = false;
    if (valid) for (int k = wid; k < n; k += 16) sup = sup | iou_gt4(kbox[k], karea2[k], q, aq);
    u64 bal = __ballot((int)sup);
    if (lane == 0) supsh[wid] = bal;
    __syncthreads();
    if (wid == 0) {
      u64 supm = 0;
      for (int w = 0; w < 16; ++w) supm |= supsh[w];
      u64 vm = __ballot((int)valid);
      u64 pending = vm & ~supm;
      u64 row = 0;
      if ((pending >> lane) & 1ull) {
        u64 mine = pending & ~((2ull << lane) - 1ull);
        while (mine) {
          int j = __builtin_ctzll(mine); mine &= mine - 1ull;
          if (iou_gt4(q, aq, cbox[j], carea[j])) row |= (1ull << j);
        }
      }
      rowsh2[lane] = row;
      u64 nz = __ballot((int)(row != 0ull));
      bool done = false;
      u64 rem = pending;
      while (rem) {
        int r = __builtin_ctzll(rem); rem &= rem - 1ull;
        if (lane == r) { kmeta[n] = meta; kbox[n] = q; karea2[n] = aq; }
        ++n;
        if (n == NDET) { done = true; break; }
        if ((nz >> r) & 1ull) rem &= ~rowsh2[r];
      }
      if (__any((int)(!valid))) done = true;
      if (lane == 0) { s_nk = (u32)n; s_stop = done ? 1u : 0u; }
    }
    __syncthreads();
    n = (int)s_nk;
  }

  // ---- emit: boxes [B,300,4] ++ scores [B,300] ++ labels [B,300] ----
  int nf = (int)s_nk;
  for (int k = tid; k < NDET; k += 1024) {
    float bx0 = 0.f, bx1 = 0.f, bx2 = 0.f, bx3 = 0.f, sc = 0.f, lb = -1.0f;
    if (k < nf) {
      u32 m = kmeta[k];
      int io = (int)(m >> 8);
      float4 v = cand_box[b * NCAND + io];
      bx0 = v.x; bx1 = v.y; bx2 = v.z; bx3 = v.w;
      sc = cand_s[b * NCAND + io];
      lb = (float)(m & 0xFFu);
    }
    int idx = b * NDET + k;
    out[(size_t)idx * 4 + 0] = bx0;
    out[(size_t)idx * 4 + 1] = bx1;
    out[(size_t)idx * 4 + 2] = bx2;
    out[(size_t)idx * 4 + 3] = bx3;
    out[NB * NDET * 4 + idx] = sc;
    out[NB * NDET * 5 + idx] = lb;
  }
}

extern "C" void kernel_launch(void* const* d_in, const int* in_sizes, int n_in,
                              void* d_out, int out_size, void* d_ws, size_t ws_size,
                              hipStream_t stream) {
  const float* cls[NLEV]; const float* reg[NLEV]; const float* anc[NLEV];
  bool dict_order = (n_in >= 2) && (in_sizes[1] == 4 * NREGCH * 64 * 64);
  for (int l = 0; l < NLEV; ++l) {
    if (dict_order) {
      cls[l] = (const float*)d_in[3 * l + 0];
      reg[l] = (const float*)d_in[3 * l + 1];
      anc[l] = (const float*)d_in[3 * l + 2];
    } else {
      cls[l] = (const float*)d_in[l];
      reg[l] = (const float*)d_in[NLEV + l];
      anc[l] = (const float*)d_in[2 * NLEV + l];
    }
  }

  char* ws = (char*)d_ws;
  size_t off = 0;
  auto alloc = [&](size_t bytes) -> void* {
    void* p = ws + off;
    off = (off + bytes + 255) & ~(size_t)255;
    return p;
  };
  u32*    bcnt     = (u32*)   alloc((size_t)NB * NCHUNK_IMG * 4);
  u64*    sel      = (u64*)   alloc(20ULL * CAP * 8);
  float*  cand_s   = (float*) alloc((size_t)NB * NCAND * 4);
  u32*    cand_t   = (u32*)   alloc((size_t)NB * NCAND * 4);
  float4* cand_box = (float4*)alloc((size_t)NB * NCAND * 16);
  float4* rboxOff  = (float4*)alloc((size_t)NB * NCAND * 16);
  u32*    rmeta    = (u32*)   alloc((size_t)NB * NCAND * 4);
  u64*    rowsG    = (u64*)   alloc((size_t)NB * DCH * DW * 8);
  (void)ws_size; (void)out_size;

  ClsPtrs cp;
  for (int l = 0; l < NLEV; ++l) cp.p[l] = cls[l];
  LevelPtrs lp;
  for (int l = 0; l < NLEV; ++l) { lp.reg[l] = reg[l]; lp.anc[l] = anc[l]; }

  k_filter<<<NB * NCHUNK_IMG, 256, 0, stream>>>(cp, bcnt, sel);
  k_rank<<<NB * NLEV, 1024, 0, stream>>>(cp, lp, bcnt, sel, cand_s, cand_t, cand_box);
  k_grank<<<dim3(NLEV, NB), 1024, 0, stream>>>(cand_s, cand_t, cand_box, rboxOff, rmeta);
  k_mask<<<dim3(DW, NB), 256, 0, stream>>>(rboxOff, rowsG);
  k_detect<<<NB, 1024, 0, stream>>>(cand_s, cand_box, rboxOff, rmeta, rowsG, (float*)d_out);
}

// Round 20
// 57.690 us; speedup vs baseline: 1.4069x; 1.0407x over previous
//
#include <hip/hip_runtime.h>
#include <stdint.h>
#include <stddef.h>

typedef unsigned int u32;
typedef unsigned long long u64;
typedef unsigned short u16;
typedef unsigned char u8;

#define NB 4
#define NLEV 5
#define NCH 72      // A*C = 9*8
#define NREGCH 36   // A*4
#define TOPK 1000
#define NCAND 5000  // NLEV*TOPK
#define NDET 300
#define NBINS 16384       // fallback hist: sigmoid float bits >> 16
#define RNB 4096          // counting-rank buckets (fast path)
#define CAP 8192          // per-(b,level) filtered-candidate buffer
#define FASTCAP 2048      // fast-path key limit (2 keys/thread @ 1024 thr)
#define CHUNK 8192
#define NCHUNK_IMG 50     // 36+9+3+1+1
#define DCH 512           // NMS rank-prefix chunk
#define DW 8              // u64 words per suppression row
#define IMGSZ 512.0f
#define SCORE_TH 0.05f
#define NMS_TH 0.5f
#define BBOX_CLIP_F 4.135166556742356f

__constant__ int c_f[NLEV]    = {64, 32, 16, 8, 4};
__constant__ int c_Nloc[NLEV] = {4096, 1024, 256, 64, 16};
__constant__ int c_lg2[NLEV]  = {12, 10, 8, 6, 4};
// logit prefilter thresholds: ~1400 expected survivors at levels 0-3 (10-sigma
// margins vs both TOPK=1000 and FASTCAP=2048); level 4 unfiltered (1152 total).
__constant__ float c_tau[NLEV] = {2.594f, 2.075f, 1.433f, 0.513f, -1e30f};
// counting-rank bucket shifts: (0x3F800000 - bits(sigmoid(tau))) >> shift < RNB
__constant__ int c_rshift[NLEV] = {10, 10, 11, 12, 18};
// per-level chunk layout inside a group's CAP region (atomic-free k_filter)
__constant__ int c_nch[NLEV]  = {36, 9, 3, 1, 1};
__constant__ int c_clo[NLEV]  = {0, 36, 45, 48, 49};
__constant__ int c_ccap[NLEV] = {227, 910, 2730, 8192, 8192};  // CAP/nch

// ---- XLA-CPU-style sigmoid: logistic(x) = 0.5 + 0.5*tanh(0.5*x), fast-tanh poly, no FMA ----
__device__ __forceinline__ float xla_tanh_f32(float x) {
  float ax = fabsf(x);
  float xc = fminf(fmaxf(x, -7.90531110763549805f), 7.90531110763549805f);
  float x2 = __fmul_rn(xc, xc);
  float p = -2.76076847742355e-16f;
  p = __fadd_rn(__fmul_rn(x2, p), 2.00018790482477e-13f);
  p = __fadd_rn(__fmul_rn(x2, p), -8.60467152213735e-11f);
  p = __fadd_rn(__fmul_rn(x2, p), 5.12229709037114e-08f);
  p = __fadd_rn(__fmul_rn(x2, p), 1.48572235717979e-05f);
  p = __fadd_rn(__fmul_rn(x2, p), 6.37261928875436e-04f);
  p = __fadd_rn(__fmul_rn(x2, p), 4.89352455891786e-03f);
  float num = __fmul_rn(xc, p);
  float q = 1.19825839466702e-06f;
  q = __fadd_rn(__fmul_rn(x2, q), 1.18534705686654e-04f);
  q = __fadd_rn(__fmul_rn(x2, q), 2.26843463243900e-03f);
  q = __fadd_rn(__fmul_rn(x2, q), 4.89352518554385e-03f);
  float r = __fdiv_rn(num, q);
  return (ax < 0.0004f) ? x : r;
}
__device__ __forceinline__ float sigmoid_ref(float x) {
  return __fadd_rn(0.5f, __fmul_rn(0.5f, xla_tanh_f32(__fmul_rn(0.5f, x))));
}

struct ClsPtrs { const float* p[NLEV]; };
struct LevelPtrs { const float* reg[NLEV]; const float* anc[NLEV]; };

__device__ __forceinline__ void chunk_map(int bid, int& b, int& level, int& chunk) {
  b = bid / NCHUNK_IMG;
  int cid = bid % NCHUNK_IMG;
  if      (cid < 36) { level = 0; chunk = cid; }
  else if (cid < 45) { level = 1; chunk = cid - 36; }
  else if (cid < 48) { level = 2; chunk = cid - 45; }
  else if (cid < 49) { level = 3; chunk = cid - 48; }
  else               { level = 4; chunk = cid - 49; }
}

// exact BoxCoder decode + clip (identical _rn sequence as all passing rounds)
__device__ __forceinline__ float4 decode_box(const LevelPtrs& lp, int b, int lv, u32 e) {
  u32 anc = e >> 3;              // loc*9 + a
  int a = (int)(anc % 9u);
  int loc = (int)(anc / 9u);
  int f = c_f[lv];
  int Nloc = f * f;
  const float* rp = lp.reg[lv];
  const float* ap = lp.anc[lv] + (size_t)anc * 4;
  float r0 = rp[((size_t)b * NREGCH + (a * 4 + 0)) * Nloc + loc];
  float r1 = rp[((size_t)b * NREGCH + (a * 4 + 1)) * Nloc + loc];
  float r2 = rp[((size_t)b * NREGCH + (a * 4 + 2)) * Nloc + loc];
  float r3 = rp[((size_t)b * NREGCH + (a * 4 + 3)) * Nloc + loc];
  float a0 = ap[0], a1 = ap[1], a2 = ap[2], a3 = ap[3];
  float aw = __fsub_rn(a2, a0);
  float ah = __fsub_rn(a3, a1);
  float acx = __fadd_rn(a0, __fmul_rn(0.5f, aw));
  float acy = __fadd_rn(a1, __fmul_rn(0.5f, ah));
  float dw = fminf(r2, BBOX_CLIP_F);
  float dh = fminf(r3, BBOX_CLIP_F);
  float pcx = __fadd_rn(__fmul_rn(r0, aw), acx);
  float pcy = __fadd_rn(__fmul_rn(r1, ah), acy);
  float pw = __fmul_rn(expf(dw), aw);
  float ph = __fmul_rn(expf(dh), ah);
  float hx = __fmul_rn(0.5f, pw);
  float hy = __fmul_rn(0.5f, ph);
  float4 v;
  v.x = fminf(fmaxf(__fsub_rn(pcx, hx), 0.0f), IMGSZ);
  v.y = fminf(fmaxf(__fsub_rn(pcy, hy), 0.0f), IMGSZ);
  v.z = fminf(fmaxf(__fadd_rn(pcx, hx), 0.0f), IMGSZ);
  v.w = fminf(fmaxf(__fadd_rn(pcy, hy), 0.0f), IMGSZ);
  return v;
}

// ---- K1: logit-prefilter, single-pass float4 register-resident, atomic-free ----
// 8x float4 loads/thread (ILP latency hiding at 1 wave/SIMD occupancy); values
// stay in registers so there is no second read pass. Survivor order within a
// chunk region is (k,tid,j) -- order-independent downstream (rank over unique
// keys; overflow guard uses counts only). Deterministic for fixed input.
__global__ __launch_bounds__(256)
void k_filter(ClsPtrs cp, u32* __restrict__ bcnt, u64* __restrict__ sel) {
  int b, level, chunk;
  chunk_map(blockIdx.x, b, level, chunk);
  int Nloc = c_Nloc[level], lg2 = c_lg2[level];
  int Nsc = Nloc * NCH;
  int g = b * NLEV + level;
  const float* cls = cp.p[level] + (size_t)b * Nsc;
  float tau = c_tau[level];
  int base = chunk * CHUNK;
  int end = base + CHUNK; if (end > Nsc) end = Nsc;
  int n4 = (end - base) >> 2;           // all Nsc here are multiples of 4
  int wid = threadIdx.x >> 6, lane = threadIdx.x & 63;
  __shared__ u32 wcnt[4];
  const float4* cls4 = (const float4*)(cls + base);
  float v[32];
  int cnt = 0;
  #pragma unroll
  for (int k = 0; k < 8; ++k) {
    int i4 = k * 256 + threadIdx.x;
    float4 x = (i4 < n4) ? cls4[i4] : make_float4(-1e30f, -1e30f, -1e30f, -1e30f);
    v[k * 4 + 0] = x.x; v[k * 4 + 1] = x.y; v[k * 4 + 2] = x.z; v[k * 4 + 3] = x.w;
    cnt += (x.x > tau) + (x.y > tau) + (x.z > tau) + (x.w > tau);
  }
  // wave inclusive scan of per-thread counts
  u32 xs = (u32)cnt;
  for (int d = 1; d < 64; d <<= 1) { u32 y = __shfl_up(xs, d); if (lane >= d) xs += y; }
  if (lane == 63) wcnt[wid] = xs;
  __syncthreads();
  u32 wbase = 0, tot = 0;
  for (int w = 0; w < 4; ++w) { u32 c = wcnt[w]; if (w < wid) wbase += c; tot += c; }
  if (threadIdx.x == 0) bcnt[blockIdx.x] = tot;   // always written: no memset needed
  if (cnt == 0) return;
  u32 ccap = (u32)c_ccap[level];
  size_t regbase = (size_t)g * CAP + (size_t)chunk * ccap;
  u32 pos = wbase + (xs - (u32)cnt);              // exclusive prefix for this thread
  #pragma unroll
  for (int k = 0; k < 8; ++k) {
    int i4 = k * 256 + threadIdx.x;
    #pragma unroll
    for (int j = 0; j < 4; ++j) {
      float xv = v[k * 4 + j];
      if (xv > tau) {
        if (pos < ccap) {
          u32 bits = __float_as_uint(sigmoid_ref(xv));
          int i = base + i4 * 4 + j;
          int ch = i >> lg2;
          int loc = i & (Nloc - 1);
          u32 e = (u32)(loc * NCH + ch);          // flat score index ((y*f+x)*9+a)*8+c
          sel[regbase + pos] = ((u64)bits << 32) | (u32)(~e);
        }
        pos++;
      }
    }
  }
}

// ---- K2: exact top-1000 via LDS counting-rank + fused decode; guarded fast path ----
__global__ __launch_bounds__(1024)
void k_rank(ClsPtrs cp, LevelPtrs lp, const u32* __restrict__ bcnt,
            const u64* __restrict__ sel,
            float* __restrict__ cand_s, u32* __restrict__ cand_t,
            float4* __restrict__ cand_box) {
  __shared__ union {
    struct { u64 keysC[FASTCAP]; u64 keys2[FASTCAP]; u32 hist[RNB]; u32 pfx[RNB]; } f; // 64 KB
    u32 histfb[NBINS];                                              // 64 KB
    u64 keysfb[CAP];                                                // 64 KB
  } sh;
  __shared__ u32 part[1024];
  __shared__ u32 ccnt[36];
  __shared__ u32 cbase[37];
  __shared__ u32 s_ovf;
  __shared__ u32 s_last;
  __shared__ u32 s_cnt;
  __shared__ int s_cut;
  int g = blockIdx.x;
  int b = g / NLEV, l = g % NLEV;
  int Nloc = c_Nloc[l], lg2 = c_lg2[l];
  int Nsc = Nloc * NCH;
  int tid = threadIdx.x;
  int lane = tid & 63;
  u64 lowm = (1ull << lane) - 1ull;
  int obase = b * NCAND + l * TOPK;
  int nch = c_nch[l], clo = c_clo[l];
  u32 ccap = (u32)c_ccap[l];
  if (tid < nch) ccnt[tid] = bcnt[b * NCHUNK_IMG + clo + tid];
  __syncthreads();
  if (tid == 0) {
    u32 a = 0, ovf = 0;
    for (int c = 0; c < nch; ++c) { cbase[c] = a; a += ccnt[c]; if (ccnt[c] > ccap) ovf = 1; }
    cbase[nch] = a; s_ovf = ovf;
  }
  __syncthreads();
  u32 cnt = cbase[nch];
  bool fast = (cnt >= TOPK) && (cnt <= FASTCAP) && !s_ovf;
  if (fast) {
    u32 m = cnt;
    int shift = c_rshift[l];
    // PARALLEL compaction: each element binary-searches its chunk via cbase
    for (u32 i = tid; i < m; i += 1024) {
      int lo = 0, h2 = nch - 1;
      while (lo < h2) { int mid = (lo + h2 + 1) >> 1; if (cbase[mid] <= i) lo = mid; else h2 = mid - 1; }
      sh.f.keysC[i] = sel[(size_t)g * CAP + (size_t)lo * ccap + (i - cbase[lo])];
    }
    for (int i = tid; i < RNB; i += 1024) sh.f.hist[i] = 0;
    if (tid == 0) s_last = 0;
    __syncthreads();
    u64 k0a = ((u32)tid < m)        ? sh.f.keysC[tid]        : 0ULL;
    u64 k0b = ((u32)tid + 1024 < m) ? sh.f.keysC[tid + 1024] : 0ULL;
    // bucket: monotone DECREASING in key; clamp handles tails exactly
    auto bkt_of = [&](u64 k) -> int {
      int d = (int)0x3F800000 - (int)(u32)(k >> 32);
      if (d < 0) d = 0;
      int bq = d >> shift;
      return bq > RNB - 1 ? RNB - 1 : bq;
    };
    int ba = bkt_of(k0a), bb = bkt_of(k0b);
    if ((u32)tid < m)        atomicAdd(&sh.f.hist[ba], 1u);
    if ((u32)tid + 1024 < m) atomicAdd(&sh.f.hist[bb], 1u);
    __syncthreads();
    // exclusive prefix scan of hist[RNB] -> pfx
    {
      int t4 = tid * 4;
      u32 h0 = sh.f.hist[t4], h1 = sh.f.hist[t4 + 1], h2 = sh.f.hist[t4 + 2], h3 = sh.f.hist[t4 + 3];
      u32 s4 = h0 + h1 + h2 + h3;
      u32 x = s4;
      for (int d = 1; d < 64; d <<= 1) { u32 y = __shfl_up(x, d); if (lane >= d) x += y; }
      if (lane == 63) part[tid >> 6] = x;
      __syncthreads();
      if (tid == 0) { u32 a = 0; for (int w = 0; w < 16; ++w) { u32 c = part[w]; part[w] = a; a += c; } }
      __syncthreads();
      u32 base2 = part[tid >> 6] + (x - s4);
      sh.f.pfx[t4]     = base2;
      sh.f.pfx[t4 + 1] = base2 + h0;
      sh.f.pfx[t4 + 2] = base2 + h0 + h1;
      sh.f.pfx[t4 + 3] = base2 + h0 + h1 + h2;
    }
    __syncthreads();
    // scatter into bucket-sorted keys2 (pfx becomes running insert ptr)
    if ((u32)tid < m)        { u32 p = atomicAdd(&sh.f.pfx[ba], 1u); sh.f.keys2[p] = k0a; }
    if ((u32)tid + 1024 < m) { u32 p = atomicAdd(&sh.f.pfx[bb], 1u); sh.f.keys2[p] = k0b; }
    __syncthreads();
    // exact rank = bucket_start + within-bucket count of greater keys; emit
    auto emit = [&](u64 k0, int bkt) {
      u32 endq = sh.f.pfx[bkt];            // after scatter: start + size
      u32 startq = endq - sh.f.hist[bkt];
      u32 r = startq;
      for (u32 j = startq; j < endq; ++j) r += (sh.f.keys2[j] > k0) ? 1u : 0u;
      if (r < TOPK) {
        u32 hi = (u32)(k0 >> 32);
        cand_s[obase + r] = __uint_as_float(hi);
        u32 e = ~((u32)k0);
        cand_t[obase + r] = ((u32)l << 19) | (e & 0x7FFFFu);
        cand_box[obase + r] = decode_box(lp, b, l, e);
        if (r == TOPK - 1) s_last = hi;
      }
    };
    if ((u32)tid < m)        emit(k0a, ba);
    if ((u32)tid + 1024 < m) emit(k0b, bb);
    __syncthreads();
    // guard: rank-999 must beat the filter boundary by >64 ulps
    u32 bits_tau = __float_as_uint(sigmoid_ref(c_tau[l]));
    if ((int)cnt != Nsc && !(s_last > bits_tau + 64u)) fast = false;  // block-uniform
  }
  if (fast) return;

  // ---- fallback (never taken for this input; exact for any input) ----
  const float* cls = cp.p[l] + (size_t)b * Nsc;
  __syncthreads();
  for (int i = tid; i < NBINS; i += 1024) sh.histfb[i] = 0;
  if (tid == 0) s_cnt = 0;
  __syncthreads();
  for (int i = tid; i < Nsc; i += 1024) {
    float s = sigmoid_ref(cls[i]);
    atomicAdd(&sh.histfb[__float_as_uint(s) >> 16], 1u);
  }
  __syncthreads();
  { u32 a = 0; for (int j = 0; j < 16; ++j) a += sh.histfb[tid * 16 + j]; part[tid] = a; }
  __syncthreads();
  if (tid == 0) {
    u32 cum = 0; int cut = 0;
    for (int ch = 1023; ch >= 0; --ch) {
      if (cum + part[ch] >= TOPK) {
        u32 cc = cum;
        for (int bin = ch * 16 + 15;; --bin) { cc += sh.histfb[bin]; if (cc >= TOPK) { cut = bin; break; } }
        break;
      }
      cum += part[ch];
    }
    s_cut = cut;
  }
  __syncthreads();
  int cut = s_cut;
  __syncthreads();                 // hist reads done before keys overwrite
  for (int i = tid; i < Nsc; i += 1024) {
    float s = sigmoid_ref(cls[i]);
    u32 bits = __float_as_uint(s);
    bool selp = (int)(bits >> 16) >= cut;
    u64 mk = __ballot((int)selp);
    if (selp) {
      int ldr = __builtin_ctzll(mk);
      u32 pos0 = 0;
      if (lane == ldr) pos0 = atomicAdd(&s_cnt, (u32)__popcll(mk));
      pos0 = (u32)__shfl((int)pos0, ldr);
      u32 pos = pos0 + (u32)__popcll(mk & lowm);
      if (pos < CAP) {
        int ch = i >> lg2;
        int loc = i & (Nloc - 1);
        u32 e = (u32)(loc * NCH + ch);
        sh.keysfb[pos] = ((u64)bits << 32) | (u32)(~e);
      }
    }
  }
  __syncthreads();
  u32 m2 = s_cnt; if (m2 > CAP) m2 = CAP;
  for (u32 i = tid; i < m2; i += 1024) {
    u64 k0 = sh.keysfb[i];
    u32 r = 0;
    #pragma unroll 8
    for (u32 j = 0; j < m2; ++j) r += (sh.keysfb[j] > k0) ? 1u : 0u;
    if (r < TOPK) {
      cand_s[obase + r] = __uint_as_float((u32)(k0 >> 32));
      u32 e = ~((u32)k0);
      cand_t[obase + r] = ((u32)l << 19) | (e & 0x7FFFFu);
      cand_box[obase + r] = decode_box(lp, b, l, e);
    }
  }
  for (u32 r = m2 + tid; r < TOPK; r += 1024) {
    cand_s[obase + r] = -1.0f;
    cand_t[obase + r] = ((u32)l << 19) | r;
    cand_box[obase + r] = make_float4(0.f, 0.f, 0.f, 0.f);
  }
}

// ---- K3: global rank per candidate (wide: 5 blocks/image); deterministic
//      invalid ranks (no atomics); scatter rank-ordered offset-box + meta. ----
__global__ __launch_bounds__(1024)
void k_grank(const float* __restrict__ cand_s, const u32* __restrict__ cand_t,
             const float4* __restrict__ cand_box,
             float4* __restrict__ rboxOff, u32* __restrict__ rmeta) {
  __shared__ u64 keys[NCAND];   // 40 KB
  __shared__ int vc[NLEV];
  int b = blockIdx.y;
  int seg = blockIdx.x;         // level list 0..4
  int tid = threadIdx.x;
  for (int i = tid; i < NCAND; i += 1024) {
    float s = cand_s[b * NCAND + i];
    u32 t = cand_t[b * NCAND + i];
    u32 hi = (s > SCORE_TH) ? __float_as_uint(s) : 0u;
    keys[i] = ((u64)hi << 32) | (u32)(~t);
  }
  __syncthreads();
  if (tid < NLEV) {             // validCnt[L] = first index with hi==0
    const u64* A = keys + tid * TOPK;
    int lo = 0, h2 = TOPK;
    while (lo < h2) { int mid = (lo + h2) >> 1; if (A[mid] >> 32) lo = mid + 1; else h2 = mid; }
    vc[tid] = lo;
  }
  __syncthreads();
  if (tid >= TOPK) return;
  int i = seg * TOPK + tid;
  u64 k0 = keys[i];
  u32 hi = (u32)(k0 >> 32);
  u32 t = ~((u32)k0);
  int rank;
  u32 cls = 0;
  if (hi) {
    rank = tid;                               // own list: earlier entries greater
    for (int L = 0; L < NLEV; ++L) {
      if (L == seg) continue;
      const u64* A = keys + L * TOPK;
      int lo = 0, h2 = TOPK;                  // count of A[j] > k0 (monotone)
      while (lo < h2) { int mid = (lo + h2) >> 1; if (A[mid] > k0) lo = mid + 1; else h2 = mid; }
      rank += lo;
    }
    cls = t & 7u;
  } else {
    int tv = 0, before = 0;
    for (int L = 0; L < NLEV; ++L) { tv += vc[L]; if (L < seg) before += TOPK - vc[L]; }
    rank = tv + before + (tid - vc[seg]);     // distinct, all >= totalValid
  }
  float4 v = cand_box[b * NCAND + i];
  float off = __fmul_rn((float)cls, IMGSZ + 1.0f);
  float4 q;
  q.x = __fadd_rn(v.x, off); q.y = __fadd_rn(v.y, off);
  q.z = __fadd_rn(v.z, off); q.w = __fadd_rn(v.w, off);
  rboxOff[b * NCAND + rank] = q;
  rmeta[b * NCAND + rank] = hi ? (((u32)i << 8) | cls) : 0xFFFFFFFFu;
}

// IoU > thresh predicate — identical _rn sequence as reference; div only when inter>0.
__device__ __forceinline__ bool iou_gt4(float4 p, float pa, float4 q, float qa) {
  float ltx = fmaxf(p.x, q.x), lty = fmaxf(p.y, q.y);
  float rx  = fminf(p.z, q.z), ry  = fminf(p.w, q.w);
  float ww = fmaxf(__fsub_rn(rx, ltx), 0.0f);
  float hh = fmaxf(__fsub_rn(ry, lty), 0.0f);
  float inter = __fmul_rn(ww, hh);
  bool res = false;
  if (inter > 0.0f) {
    float denom = fmaxf(__fsub_rn(__fadd_rn(pa, qa), inter), 1e-7f);
    res = __fdiv_rn(inter, denom) > NMS_TH;
  }
  return res;
}
__device__ __forceinline__ float area_rn(float4 p) {
  return __fmul_rn(__fsub_rn(p.z, p.x), __fsub_rn(p.w, p.y));
}

// ---- K4: wide suppression-matrix build over the 512-rank prefix ----
__global__ __launch_bounds__(256)
void k_mask(const float4* __restrict__ rboxOff, u64* __restrict__ rowsG) {
  __shared__ float4 sb[DCH];   // 8 KB offset boxes
  __shared__ float  sa[DCH];   // 2 KB areas
  int b = blockIdx.y, rb = blockIdx.x;   // row-block: rows rb*64 .. rb*64+63
  int tid = threadIdx.x;
  for (int i = tid; i < DCH; i += 256) {
    float4 q = rboxOff[b * NCAND + i];
    sb[i] = q; sa[i] = area_rn(q);
  }
  __syncthreads();
  int lane = tid & 63, wv = tid >> 6;
  int r = rb * 64 + lane;
  float4 qr = sb[r]; float ar = sa[r];
  u64* rowp = rowsG + ((size_t)b * DCH + r) * DW;
  for (int w = wv; w < rb; w += 4) rowp[w] = 0;
  for (int w = rb + wv; w < DW; w += 4) {
    u64 bits = 0;
    int j0 = w * 64;
    if (w > rb) {
      #pragma unroll 4
      for (int jc = 0; jc < 64; ++jc)
        if (iou_gt4(qr, ar, sb[j0 + jc], sa[j0 + jc])) bits |= 1ull << jc;
    } else {                                // diagonal word: guard j > r
      #pragma unroll 4
      for (int jc = 0; jc < 64; ++jc) {
        int j = j0 + jc;
        if (j > r && iou_gt4(qr, ar, sb[j], sa[j])) bits |= 1ull << jc;
      }
    }
    rowp[w] = bits;
  }
}

// ---- K5: scalar greedy over precomputed matrix + append + emit; exact fallback ----
__global__ __launch_bounds__(1024)
void k_detect(const float* __restrict__ cand_s, const float4* __restrict__ cand_box,
              const float4* __restrict__ rboxOff, const u32* __restrict__ rmeta,
              const u64* __restrict__ rowsG, float* __restrict__ out) {
  __shared__ u64 rows[DCH][DW];     // 32 KB
  __shared__ u32 sm[DCH];           //  2 KB
  __shared__ u32 nzmap[DCH / 32];
  __shared__ u64 validm[DW], keptm[DW];
  __shared__ float4 kbox[NDET];     // kept offset boxes (fallback phase A)
  __shared__ float  karea2[NDET];
  __shared__ u32    kmeta[NDET];
  __shared__ float4 cbox[64];
  __shared__ float  carea[64];
  __shared__ u64    supsh[16];
  __shared__ u64    rowsh2[64];
  __shared__ u32 s_nk, s_stop;
  int b = blockIdx.x, tid = threadIdx.x;
  int lane = tid & 63, wid = tid >> 6;
  if (tid < DCH / 32) nzmap[tid] = 0;
  if (tid == 0) { s_nk = 0; s_stop = 0; }
  __syncthreads();
  for (int k = tid; k < DCH * DW; k += 1024) {
    u64 v = rowsG[(size_t)b * DCH * DW + k];
    ((u64*)rows)[k] = v;
    if (v) atomicOr(&nzmap[(k / DW) >> 5], 1u << ((k / DW) & 31));
  }
  if (tid < DCH) sm[tid] = rmeta[b * NCAND + tid];
  __syncthreads();
  if (tid < DCH) {
    u64 bv = __ballot((int)(sm[tid] != 0xFFFFFFFFu));
    if (lane == 0) validm[tid >> 6] = bv;
  }
  __syncthreads();
  if (tid == 0) {
    u64 kw[DW];
    #pragma unroll
    for (int w = 0; w < DW; ++w) kw[w] = validm[w];
    for (int mw = 0; mw < DCH / 32; ++mw) {
      u32 nzw = nzmap[mw];
      while (nzw) {
        int bit = __builtin_ctz(nzw); nzw &= nzw - 1;
        int i = mw * 32 + bit;
        if ((kw[i >> 6] >> (i & 63)) & 1ull) {
          #pragma unroll
          for (int v = 0; v < DW; ++v) kw[v] &= ~rows[i][v];
        }
      }
    }
    #pragma unroll
    for (int w = 0; w < DW; ++w) keptm[w] = kw[w];
  }
  __syncthreads();
  if (tid < DCH) {
    int w = tid >> 6;
    u64 kwv = keptm[w];
    if ((kwv >> (tid & 63)) & 1ull) {
      u32 pre = 0;
      for (int v = 0; v < w; ++v) pre += (u32)__popcll(keptm[v]);
      pre += (u32)__popcll(kwv & ((1ull << (tid & 63)) - 1ull));
      if (pre < NDET) {
        float4 q = rboxOff[b * NCAND + tid];
        kbox[pre] = q; karea2[pre] = area_rn(q); kmeta[pre] = sm[tid];
      }
    }
  }
  __syncthreads();
  if (tid == 0) {
    u32 add = 0, nvalid = 0;
    #pragma unroll
    for (int w = 0; w < DW; ++w) { add += (u32)__popcll(keptm[w]); nvalid += (u32)__popcll(validm[w]); }
    u32 nn = add; if (nn > NDET) nn = NDET;
    s_nk = nn;
    if (nn >= (u32)NDET || nvalid < (u32)DCH) s_stop = 1;
  }
  __syncthreads();

  // ---- fallback for ranks >= DCH (rare; exact greedy, single combined kept list) ----
  int n = (int)s_nk;
  for (int base = DCH; base < NCAND && !s_stop; base += 64) {
    int ci = base + lane;
    u32 meta = (ci < NCAND) ? rmeta[b * NCAND + ci] : 0xFFFFFFFFu;
    bool valid = meta != 0xFFFFFFFFu;
    float4 q = (ci < NCAND) ? rboxOff[b * NCAND + ci] : make_float4(0.f, 0.f, 0.f, 0.f);
    float aq = area_rn(q);
    if (wid == 0) { cbox[lane] = q; carea[lane] = aq; }
    bool sup = false;
    if (valid) for (int k = wid; k < n; k += 16) sup = sup | iou_gt4(kbox[k], karea2[k], q, aq);
    u64 bal = __ballot((int)sup);
    if (lane == 0) supsh[wid] = bal;
    __syncthreads();
    if (wid == 0) {
      u64 supm = 0;
      for (int w = 0; w < 16; ++w) supm |= supsh[w];
      u64 vm = __ballot((int)valid);
      u64 pending = vm & ~supm;
      u64 row = 0;
      if ((pending >> lane) & 1ull) {
        u64 mine = pending & ~((2ull << lane) - 1ull);
        while (mine) {
          int j = __builtin_ctzll(mine); mine &= mine - 1ull;
          if (iou_gt4(q, aq, cbox[j], carea[j])) row |= (1ull << j);
        }
      }
      rowsh2[lane] = row;
      u64 nz = __ballot((int)(row != 0ull));
      bool done = false;
      u64 rem = pending;
      while (rem) {
        int r = __builtin_ctzll(rem); rem &= rem - 1ull;
        if (lane == r) { kmeta[n] = meta; kbox[n] = q; karea2[n] = aq; }
        ++n;
        if (n == NDET) { done = true; break; }
        if ((nz >> r) & 1ull) rem &= ~rowsh2[r];
      }
      if (__any((int)(!valid))) done = true;
      if (lane == 0) { s_nk = (u32)n; s_stop = done ? 1u : 0u; }
    }
    __syncthreads();
    n = (int)s_nk;
  }

  // ---- emit: boxes [B,300,4] ++ scores [B,300] ++ labels [B,300] ----
  int nf = (int)s_nk;
  for (int k = tid; k < NDET; k += 1024) {
    float bx0 = 0.f, bx1 = 0.f, bx2 = 0.f, bx3 = 0.f, sc = 0.f, lb = -1.0f;
    if (k < nf) {
      u32 m = kmeta[k];
      int io = (int)(m >> 8);
      float4 v = cand_box[b * NCAND + io];
      bx0 = v.x; bx1 = v.y; bx2 = v.z; bx3 = v.w;
      sc = cand_s[b * NCAND + io];
      lb = (float)(m & 0xFFu);
    }
    int idx = b * NDET + k;
    out[(size_t)idx * 4 + 0] = bx0;
    out[(size_t)idx * 4 + 1] = bx1;
    out[(size_t)idx * 4 + 2] = bx2;
    out[(size_t)idx * 4 + 3] = bx3;
    out[NB * NDET * 4 + idx] = sc;
    out[NB * NDET * 5 + idx] = lb;
  }
}

extern "C" void kernel_launch(void* const* d_in, const int* in_sizes, int n_in,
                              void* d_out, int out_size, void* d_ws, size_t ws_size,
                              hipStream_t stream) {
  const float* cls[NLEV]; const float* reg[NLEV]; const float* anc[NLEV];
  bool dict_order = (n_in >= 2) && (in_sizes[1] == 4 * NREGCH * 64 * 64);
  for (int l = 0; l < NLEV; ++l) {
    if (dict_order) {
      cls[l] = (const float*)d_in[3 * l + 0];
      reg[l] = (const float*)d_in[3 * l + 1];
      anc[l] = (const float*)d_in[3 * l + 2];
    } else {
      cls[l] = (const float*)d_in[l];
      reg[l] = (const float*)d_in[NLEV + l];
      anc[l] = (const float*)d_in[2 * NLEV + l];
    }
  }

  char* ws = (char*)d_ws;
  size_t off = 0;
  auto alloc = [&](size_t bytes) -> void* {
    void* p = ws + off;
    off = (off + bytes + 255) & ~(size_t)255;
    return p;
  };
  u32*    bcnt     = (u32*)   alloc((size_t)NB * NCHUNK_IMG * 4);
  u64*    sel      = (u64*)   alloc(20ULL * CAP * 8);
  float*  cand_s   = (float*) alloc((size_t)NB * NCAND * 4);
  u32*    cand_t   = (u32*)   alloc((size_t)NB * NCAND * 4);
  float4* cand_box = (float4*)alloc((size_t)NB * NCAND * 16);
  float4* rboxOff  = (float4*)alloc((size_t)NB * NCAND * 16);
  u32*    rmeta    = (u32*)   alloc((size_t)NB * NCAND * 4);
  u64*    rowsG    = (u64*)   alloc((size_t)NB * DCH * DW * 8);
  (void)ws_size; (void)out_size;

  ClsPtrs cp;
  for (int l = 0; l < NLEV; ++l) cp.p[l] = cls[l];
  LevelPtrs lp;
  for (int l = 0; l < NLEV; ++l) { lp.reg[l] = reg[l]; lp.anc[l] = anc[l]; }

  k_filter<<<NB * NCHUNK_IMG, 256, 0, stream>>>(cp, bcnt, sel);
  k_rank<<<NB * NLEV, 1024, 0, stream>>>(cp, lp, bcnt, sel, cand_s, cand_t, cand_box);
  k_grank<<<dim3(NLEV, NB), 1024, 0, stream>>>(cand_s, cand_t, cand_box, rboxOff, rmeta);
  k_mask<<<dim3(DW, NB), 256, 0, stream>>>(rboxOff, rowsG);
  k_detect<<<NB, 1024, 0, stream>>>(cand_s, cand_box, rboxOff, rmeta, rowsG, (float*)d_out);
}